// Round 6
// baseline (260.800 us; speedup 1.0000x reference)
//
#include <hip/hip_runtime.h>
#include <hip/hip_bf16.h>

// Problem dims (fixed by reference)
#define BB 8
#define NN 2048
#define DD 256
#define MM (BB * NN)   // 16384 rows
#define CAP 512        // per-wave neighbor-list capacity (typical cnt ~37)

typedef __attribute__((ext_vector_type(8))) short bf16x8_t;  // 8 bf16 = 4 VGPRs
typedef __attribute__((ext_vector_type(4))) float f32x4_t;

// ---------------------------------------------------------------------------
// Kernel A: h = x @ W^T + b. fp32 inputs, converted to bf16 at LDS staging,
// bf16 MFMA w/ fp32 accumulate, h written as bf16 (workspace).
// grid (M/64, 256/64), block 256 (4 waves).
// ---------------------------------------------------------------------------
__global__ __launch_bounds__(256) void gemm_h(
    const float* __restrict__ x,     // [M,256] fp32
    const float* __restrict__ Wt,    // [256,256] fp32 row-major [out,in] (B^T form)
    const float* __restrict__ bias,  // [256] fp32
    __hip_bfloat16* __restrict__ h)  // [M,256] bf16
{
    __shared__ __hip_bfloat16 As[64][72];
    __shared__ __hip_bfloat16 Bs[64][72];

    const int tid  = threadIdx.x;
    const int r    = tid >> 2;          // 0..63 staging row
    const int cs   = (tid & 3) * 16;    // k-segment 0/16/32/48
    const int w    = tid >> 6;          // wave 0..3
    const int lane = tid & 63;
    const int m16  = lane & 15;
    const int quad = lane >> 4;
    const long rowBase = (long)blockIdx.x * 64;
    const int  colBase = blockIdx.y * 64;

    f32x4_t acc[4];
#pragma unroll
    for (int c = 0; c < 4; c++) acc[c] = (f32x4_t){0.f, 0.f, 0.f, 0.f};

    for (int k0 = 0; k0 < 256; k0 += 64) {
        const float4* ag = (const float4*)(x  + (rowBase + r) * 256 + k0 + cs);
        const float4* bg = (const float4*)(Wt + (long)(colBase + r) * 256 + k0 + cs);
        float4 av[4], bv[4];
#pragma unroll
        for (int q = 0; q < 4; q++) { av[q] = ag[q]; bv[q] = bg[q]; }

        __align__(16) __hip_bfloat16 ta[16], tb[16];
#pragma unroll
        for (int q = 0; q < 4; q++) {
            ta[q * 4 + 0] = __float2bfloat16(av[q].x);
            ta[q * 4 + 1] = __float2bfloat16(av[q].y);
            ta[q * 4 + 2] = __float2bfloat16(av[q].z);
            ta[q * 4 + 3] = __float2bfloat16(av[q].w);
            tb[q * 4 + 0] = __float2bfloat16(bv[q].x);
            tb[q * 4 + 1] = __float2bfloat16(bv[q].y);
            tb[q * 4 + 2] = __float2bfloat16(bv[q].z);
            tb[q * 4 + 3] = __float2bfloat16(bv[q].w);
        }

        __syncthreads();
        *(uint4*)&As[r][cs]     = *(uint4*)&ta[0];
        *(uint4*)&As[r][cs + 8] = *(uint4*)&ta[8];
        *(uint4*)&Bs[r][cs]     = *(uint4*)&tb[0];
        *(uint4*)&Bs[r][cs + 8] = *(uint4*)&tb[8];
        __syncthreads();

#pragma unroll
        for (int kk = 0; kk < 64; kk += 32) {
            bf16x8_t af = *(const bf16x8_t*)&As[w * 16 + m16][kk + quad * 8];
#pragma unroll
            for (int c = 0; c < 4; c++) {
                bf16x8_t bf = *(const bf16x8_t*)&Bs[c * 16 + m16][kk + quad * 8];
                acc[c] = __builtin_amdgcn_mfma_f32_16x16x32_bf16(af, bf, acc[c], 0, 0, 0);
            }
        }
    }

    // Epilogue: C/D layout col = lane&15 (N side), row = quad*4 + reg (M side)
#pragma unroll
    for (int c = 0; c < 4; c++) {
        const int col = colBase + c * 16 + m16;
        const float bv = bias[col];
#pragma unroll
        for (int reg = 0; reg < 4; reg++) {
            const long row = rowBase + w * 16 + quad * 4 + reg;
            h[row * 256 + col] = __float2bfloat16(acc[c][reg] + bv);
        }
    }
}

// ---------------------------------------------------------------------------
// Kernel B: per row: s1b = h@a1 + att_b ; t2 = mask ? h@a2 : -1e30.
// One wave per row. t2 folds the j-side mask so attn_agg's scan is branchless:
// sigmoid(si + (-1e30)) == rcp(+inf) == 0 exactly -> masked edges drop out.
// ---------------------------------------------------------------------------
struct __attribute__((aligned(8))) bf4 { __hip_bfloat16 v[4]; };

__global__ __launch_bounds__(256) void s_kernel(
    const __hip_bfloat16* __restrict__ h,
    const float* __restrict__ a1,
    const float* __restrict__ a2,
    const float* __restrict__ mask,
    const float* __restrict__ attb_p,
    float* __restrict__ s1b, float* __restrict__ t2)
{
    const int w = threadIdx.x >> 6;
    const int lane = threadIdx.x & 63;
    const long row = (long)blockIdx.x * 4 + w;

    bf4 hv = *(const bf4*)(h + row * 256 + lane * 4);
    float4 A1 = *(const float4*)(a1 + lane * 4);
    float4 A2 = *(const float4*)(a2 + lane * 4);
    const float h0 = __bfloat162float(hv.v[0]), h1 = __bfloat162float(hv.v[1]);
    const float h2 = __bfloat162float(hv.v[2]), h3 = __bfloat162float(hv.v[3]);
    float p1 = h0 * A1.x + h1 * A1.y + h2 * A1.z + h3 * A1.w;
    float p2 = h0 * A2.x + h1 * A2.y + h2 * A2.z + h3 * A2.w;
#pragma unroll
    for (int off = 32; off; off >>= 1) {
        p1 += __shfl_down(p1, off);
        p2 += __shfl_down(p2, off);
    }
    if (lane == 0) {
        s1b[row] = p1 + attb_p[0];
        t2[row]  = (mask[row] != 0.f) ? p2 : -1e30f;
    }
}

// ---------------------------------------------------------------------------
// Kernel C: sparse attention aggregate — WAVE-AUTONOMOUS, zero barriers.
// One wave (64 lanes) per (b,i) row; block = 4 waves on 4 consecutive rows of
// the same batch. Scan: coalesced float4 adj+t2 sweeps, branchless sigmoid,
// exec-masked append to a per-wave LDS list. Denominator: shuffle reduce.
// Gather: lane owns channels [4l,4l+4) via one uint2 (8B) load per neighbor,
// 8 in flight. Overflow (cnt>CAP, impossible for 2% density but kept for
// correctness): ballot+shfl broadcast slow path, list ignored.
// b = blockIdx & 7 keeps each batch's 1 MB h slice hot in one XCD's L2.
// ---------------------------------------------------------------------------
__global__ __launch_bounds__(256, 8) void attn_agg(
    const float* __restrict__ adj,
    const float* __restrict__ mask,
    const __hip_bfloat16* __restrict__ h,
    const float* __restrict__ s1b,
    const float* __restrict__ t2,
    float* __restrict__ out)
{
    __shared__ float2 s_list[4][CAP];   // .x = byte offset (j<<9) bits, .y = weight
    __shared__ int    s_cnt[4];

    const int tid  = threadIdx.x;
    const int wv   = tid >> 6;
    const int lane = tid & 63;
    const int b    = blockIdx.x & 7;
    const int i    = ((blockIdx.x >> 3) << 2) + wv;
    const long row   = (long)b * NN + i;
    const long mbase = (long)b * NN;

    float4* orow = (float4*)(out + row * 256);

    const float mask_i = mask[row];
    if (mask_i == 0.f) {                 // wave-uniform; no barriers in this kernel
        orow[lane] = make_float4(0.f, 0.f, 0.f, 0.f);
        return;
    }
    if (lane == 0) s_cnt[wv] = 0;

    const float si = s1b[row];
    const float4* arow = (const float4*)(adj + row * NN);
    const float4* trow = (const float4*)(t2 + mbase);

    float lsum = 0.f;
    int   lcnt = 0;
#pragma unroll 4
    for (int q = 0; q < 8; q++) {
        const float4 A = arow[q * 64 + lane];   // coalesced 1KB per wave
        const float4 T = trow[q * 64 + lane];   // L1/L2-hot (8KB slice)
        const int jb = (q * 256 + lane * 4) << 9;
        const float av[4] = {A.x, A.y, A.z, A.w};
        const float tv[4] = {T.x, T.y, T.z, T.w};
#pragma unroll
        for (int e = 0; e < 4; e++) {
            const float z   = si + tv[e];
            const float sig = __builtin_amdgcn_rcpf(1.f + __expf(-z)); // rcp(inf)=0 for masked j
            const float wgt = av[e] * sig;
            lsum += wgt;
            if (wgt != 0.f) {            // exec-masked append, ~1 active lane/iter
                lcnt++;
                const int pos = atomicAdd(&s_cnt[wv], 1);
                if (pos < CAP)
                    s_list[wv][pos] = make_float2(__int_as_float(jb + (e << 9)), wgt);
            }
        }
    }

    // wave-level reductions (no LDS, no barrier)
#pragma unroll
    for (int off = 32; off; off >>= 1) {
        lsum += __shfl_down(lsum, off);
        lcnt += __shfl_down(lcnt, off);
    }
    const float inv = 1.f / (__shfl(lsum, 0) + 1e-8f);
    const int   cnt = __shfl(lcnt, 0);

    const char* hb  = (const char*)(h + mbase * 256);  // wave-uniform -> SGPR base
    const int  loff = lane * 8;                        // lane owns channels [4l,4l+4)
    float ax = 0.f, ay = 0.f, az = 0.f, aw = 0.f;

    if (cnt <= CAP) {
        const float2* lst = &s_list[wv][0];
        int k = 0;
        for (; k + 8 <= cnt; k += 8) {
            float2 ee[8];
#pragma unroll
            for (int q = 0; q < 8; q++) ee[q] = lst[k + q];    // broadcast ds_read_b64
            uint2 u[8];
#pragma unroll
            for (int q = 0; q < 8; q++)
                u[q] = *(const uint2*)(hb + __float_as_int(ee[q].x) + loff);
#pragma unroll
            for (int q = 0; q < 8; q++) {
                ax += ee[q].y * __uint_as_float(u[q].x << 16);
                ay += ee[q].y * __uint_as_float(u[q].x & 0xffff0000u);
                az += ee[q].y * __uint_as_float(u[q].y << 16);
                aw += ee[q].y * __uint_as_float(u[q].y & 0xffff0000u);
            }
        }
        for (; k < cnt; k++) {
            float2 ee = lst[k];
            uint2 u = *(const uint2*)(hb + __float_as_int(ee.x) + loff);
            ax += ee.y * __uint_as_float(u.x << 16);
            ay += ee.y * __uint_as_float(u.x & 0xffff0000u);
            az += ee.y * __uint_as_float(u.y << 16);
            aw += ee.y * __uint_as_float(u.y & 0xffff0000u);
        }
    } else {
        // correctness-only slow path (never taken at 2% density): re-scan and
        // broadcast each edge to the whole wave via ballot + shfl.
        for (int q = 0; q < 8; q++) {
            const float4 A = arow[q * 64 + lane];
            const float4 T = trow[q * 64 + lane];
            const float av[4] = {A.x, A.y, A.z, A.w};
            const float tv[4] = {T.x, T.y, T.z, T.w};
            for (int e = 0; e < 4; e++) {
                const float z   = si + tv[e];
                const float sig = __builtin_amdgcn_rcpf(1.f + __expf(-z));
                const float wgt = av[e] * sig;
                const int   j   = q * 256 + lane * 4 + e;
                unsigned long long bm = __ballot(wgt != 0.f);
                while (bm) {
                    const int s  = __ffsll((long long)bm) - 1;
                    const float ww = __shfl(wgt, s);
                    const int   jj = __shfl(j, s);
                    uint2 u = *(const uint2*)(hb + (jj << 9) + loff);
                    ax += ww * __uint_as_float(u.x << 16);
                    ay += ww * __uint_as_float(u.x & 0xffff0000u);
                    az += ww * __uint_as_float(u.y << 16);
                    aw += ww * __uint_as_float(u.y & 0xffff0000u);
                    bm &= bm - 1;
                }
            }
        }
    }

    orow[lane] = make_float4(ax * inv, ay * inv, az * inv, aw * inv);
}

// ---------------------------------------------------------------------------
extern "C" void kernel_launch(void* const* d_in, const int* in_sizes, int n_in,
                              void* d_out, int out_size, void* d_ws, size_t ws_size,
                              hipStream_t stream) {
    const float* x    = (const float*)d_in[0];
    const float* adj  = (const float*)d_in[1];
    const float* mask = (const float*)d_in[2];
    const float* W    = (const float*)d_in[3];
    const float* bias = (const float*)d_in[4];
    const float* a1   = (const float*)d_in[5];
    const float* a2   = (const float*)d_in[6];
    const float* attb = (const float*)d_in[7];
    float* out = (float*)d_out;

    // workspace: h bf16 [16384*256] (8 MB) | s1b fp32 [16384] | t2 fp32 [16384]
    __hip_bfloat16* h = (__hip_bfloat16*)d_ws;
    float* s1b = (float*)((char*)d_ws + (size_t)MM * DD * 2);
    float* t2  = s1b + MM;

    gemm_h<<<dim3(MM / 64, DD / 64), 256, 0, stream>>>(x, W, bias, h);
    s_kernel<<<MM / 4, 256, 0, stream>>>(h, a1, a2, mask, attb, s1b, t2);
    attn_agg<<<MM / 4, 256, 0, stream>>>(adj, mask, h, s1b, t2, out);
}

// Round 7
// 256.866 us; speedup vs baseline: 1.0153x; 1.0153x over previous
//
#include <hip/hip_runtime.h>
#include <hip/hip_bf16.h>

// Problem dims (fixed by reference)
#define BB 8
#define NN 2048
#define DD 256
#define MM (BB * NN)   // 16384 rows

typedef __attribute__((ext_vector_type(8))) short bf16x8_t;  // 8 bf16 = 4 VGPRs
typedef __attribute__((ext_vector_type(4))) float f32x4_t;

// ---------------------------------------------------------------------------
// Kernel A: h = x @ W^T + b. fp32 inputs, converted to bf16 at LDS staging,
// bf16 MFMA w/ fp32 accumulate, h written as bf16 (workspace).
// grid (M/64, 256/64), block 256 (4 waves).
// ---------------------------------------------------------------------------
__global__ __launch_bounds__(256) void gemm_h(
    const float* __restrict__ x,     // [M,256] fp32
    const float* __restrict__ Wt,    // [256,256] fp32 row-major [out,in] (B^T form)
    const float* __restrict__ bias,  // [256] fp32
    __hip_bfloat16* __restrict__ h)  // [M,256] bf16
{
    __shared__ __hip_bfloat16 As[64][72];
    __shared__ __hip_bfloat16 Bs[64][72];

    const int tid  = threadIdx.x;
    const int r    = tid >> 2;          // 0..63 staging row
    const int cs   = (tid & 3) * 16;    // k-segment 0/16/32/48
    const int w    = tid >> 6;          // wave 0..3
    const int lane = tid & 63;
    const int m16  = lane & 15;
    const int quad = lane >> 4;
    const long rowBase = (long)blockIdx.x * 64;
    const int  colBase = blockIdx.y * 64;

    f32x4_t acc[4];
#pragma unroll
    for (int c = 0; c < 4; c++) acc[c] = (f32x4_t){0.f, 0.f, 0.f, 0.f};

    for (int k0 = 0; k0 < 256; k0 += 64) {
        const float4* ag = (const float4*)(x  + (rowBase + r) * 256 + k0 + cs);
        const float4* bg = (const float4*)(Wt + (long)(colBase + r) * 256 + k0 + cs);
        float4 av[4], bv[4];
#pragma unroll
        for (int q = 0; q < 4; q++) { av[q] = ag[q]; bv[q] = bg[q]; }

        __align__(16) __hip_bfloat16 ta[16], tb[16];
#pragma unroll
        for (int q = 0; q < 4; q++) {
            ta[q * 4 + 0] = __float2bfloat16(av[q].x);
            ta[q * 4 + 1] = __float2bfloat16(av[q].y);
            ta[q * 4 + 2] = __float2bfloat16(av[q].z);
            ta[q * 4 + 3] = __float2bfloat16(av[q].w);
            tb[q * 4 + 0] = __float2bfloat16(bv[q].x);
            tb[q * 4 + 1] = __float2bfloat16(bv[q].y);
            tb[q * 4 + 2] = __float2bfloat16(bv[q].z);
            tb[q * 4 + 3] = __float2bfloat16(bv[q].w);
        }

        __syncthreads();
        *(uint4*)&As[r][cs]     = *(uint4*)&ta[0];
        *(uint4*)&As[r][cs + 8] = *(uint4*)&ta[8];
        *(uint4*)&Bs[r][cs]     = *(uint4*)&tb[0];
        *(uint4*)&Bs[r][cs + 8] = *(uint4*)&tb[8];
        __syncthreads();

#pragma unroll
        for (int kk = 0; kk < 64; kk += 32) {
            bf16x8_t af = *(const bf16x8_t*)&As[w * 16 + m16][kk + quad * 8];
#pragma unroll
            for (int c = 0; c < 4; c++) {
                bf16x8_t bf = *(const bf16x8_t*)&Bs[c * 16 + m16][kk + quad * 8];
                acc[c] = __builtin_amdgcn_mfma_f32_16x16x32_bf16(af, bf, acc[c], 0, 0, 0);
            }
        }
    }

    // Epilogue: C/D layout col = lane&15 (N side), row = quad*4 + reg (M side)
#pragma unroll
    for (int c = 0; c < 4; c++) {
        const int col = colBase + c * 16 + m16;
        const float bv = bias[col];
#pragma unroll
        for (int reg = 0; reg < 4; reg++) {
            const long row = rowBase + w * 16 + quad * 4 + reg;
            h[row * 256 + col] = __float2bfloat16(acc[c][reg] + bv);
        }
    }
}

// ---------------------------------------------------------------------------
// Kernel B: per row: s1b = h@a1 + att_b ; t2 = mask ? h@a2 : -1e30.
// One wave per row. t2 folds the j-side mask so attn_agg's scan is branchless:
// sigmoid(si + (-1e30)) == rcp(+inf) == 0 exactly -> masked edges drop out.
// ---------------------------------------------------------------------------
struct __attribute__((aligned(8))) bf4 { __hip_bfloat16 v[4]; };

__global__ __launch_bounds__(256) void s_kernel(
    const __hip_bfloat16* __restrict__ h,
    const float* __restrict__ a1,
    const float* __restrict__ a2,
    const float* __restrict__ mask,
    const float* __restrict__ attb_p,
    float* __restrict__ s1b, float* __restrict__ t2)
{
    const int w = threadIdx.x >> 6;
    const int lane = threadIdx.x & 63;
    const long row = (long)blockIdx.x * 4 + w;

    bf4 hv = *(const bf4*)(h + row * 256 + lane * 4);
    float4 A1 = *(const float4*)(a1 + lane * 4);
    float4 A2 = *(const float4*)(a2 + lane * 4);
    const float h0 = __bfloat162float(hv.v[0]), h1 = __bfloat162float(hv.v[1]);
    const float h2 = __bfloat162float(hv.v[2]), h3 = __bfloat162float(hv.v[3]);
    float p1 = h0 * A1.x + h1 * A1.y + h2 * A1.z + h3 * A1.w;
    float p2 = h0 * A2.x + h1 * A2.y + h2 * A2.z + h3 * A2.w;
#pragma unroll
    for (int off = 32; off; off >>= 1) {
        p1 += __shfl_down(p1, off);
        p2 += __shfl_down(p2, off);
    }
    if (lane == 0) {
        s1b[row] = p1 + attb_p[0];
        t2[row]  = (mask[row] != 0.f) ? p2 : -1e30f;
    }
}

// ---------------------------------------------------------------------------
// Kernel C: sparse attention aggregate (v7). One block per (b,i) row, 256 thr.
//  - scan (R5-proven): coalesced float4 adj+t2, branchless sigmoid
//    (rcp(1+exp(-z)); rcp(inf)=0 drops masked j), exec-masked append to ONE
//    shared list. Capacity 2048 == row length -> overflow impossible.
//  - gather split by CHANNELS: wave wv owns channels [64wv,64wv+64), lane owns
//    one channel, iterates the FULL list with 8 ushort loads in flight.
//    No cross-wave combine, no post-gather barrier; 2 barriers total.
//  - max parallelism: 16384 blocks, 65536 waves (R6 lesson: throughput here
//    = outstanding requests; wave-autonomy at 1/4 the waves regressed).
// b = blockIdx & 7 keeps each batch's 1 MB h slice hot in one XCD's L2.
// ---------------------------------------------------------------------------
__global__ __launch_bounds__(256, 8) void attn_agg(
    const float* __restrict__ adj,
    const float* __restrict__ mask,
    const __hip_bfloat16* __restrict__ h,
    const float* __restrict__ s1b,
    const float* __restrict__ t2,
    float* __restrict__ out)
{
    __shared__ float2 s_list[2048];   // .x = byte offset (j<<9) bits, .y = weight
    __shared__ int    s_cnt;
    __shared__ float  s_sum[4];

    const int tid  = threadIdx.x;
    const int wv   = tid >> 6;
    const int lane = tid & 63;
    const int b    = blockIdx.x & 7;
    const int i    = blockIdx.x >> 3;
    const long row   = (long)b * NN + i;
    const long mbase = (long)b * NN;

    const float mask_i = mask[row];
    if (mask_i == 0.f) {                  // block-uniform early exit
        out[row * 256 + tid] = 0.f;
        return;
    }
    if (tid == 0) s_cnt = 0;
    __syncthreads();

    const float si = s1b[row];
    const float4* arow = (const float4*)(adj + row * NN);
    const float4* trow = (const float4*)(t2 + mbase);

    float4 A0 = arow[tid], A1 = arow[256 + tid];   // coalesced; j = tid*4.. / 1024+tid*4..
    float4 T0 = trow[tid], T1 = trow[256 + tid];   // 64 KB array, L1/L2-hot

    float lsum = 0.f;
#pragma unroll
    for (int g = 0; g < 2; g++) {
        const int jb = (g * 1024 + tid * 4) << 9;
        const float av[4] = {g ? A1.x : A0.x, g ? A1.y : A0.y, g ? A1.z : A0.z, g ? A1.w : A0.w};
        const float tv[4] = {g ? T1.x : T0.x, g ? T1.y : T0.y, g ? T1.z : T0.z, g ? T1.w : T0.w};
#pragma unroll
        for (int e = 0; e < 4; e++) {
            const float z   = si + tv[e];
            const float sig = __builtin_amdgcn_rcpf(1.f + __expf(-z));
            const float wgt = av[e] * sig;
            lsum += wgt;
            if (wgt != 0.f) {             // exec-masked append, ~4.6 active lanes/block-iter
                const int pos = atomicAdd(&s_cnt, 1);
                s_list[pos] = make_float2(__int_as_float(jb + (e << 9)), wgt);
            }
        }
    }

    // per-wave partial denominator -> LDS; single post-scan barrier
#pragma unroll
    for (int off = 32; off; off >>= 1) lsum += __shfl_down(lsum, off);
    if (lane == 0) s_sum[wv] = lsum;
    __syncthreads();

    const float inv = 1.f / (s_sum[0] + s_sum[1] + s_sum[2] + s_sum[3] + 1e-8f);
    const int   cnt = s_cnt;              // <= 2048 structurally

    // ---- gather: lane owns channel c = wv*64 + lane (byte offset tid*2) ----
    const char* hb   = (const char*)(h + mbase * 256);   // block-uniform -> SGPR base
    const int   coff = tid * 2;
    float acc = 0.f;
    int k = 0;
    for (; k + 8 <= cnt; k += 8) {
        float4 e[4];
#pragma unroll
        for (int q = 0; q < 4; q++) e[q] = *(const float4*)&s_list[k + q * 2]; // 2 nbrs per b128
        unsigned short u[8];
#pragma unroll
        for (int q = 0; q < 4; q++) {
            u[q * 2]     = *(const unsigned short*)(hb + __float_as_int(e[q].x) + coff);
            u[q * 2 + 1] = *(const unsigned short*)(hb + __float_as_int(e[q].z) + coff);
        }
#pragma unroll
        for (int q = 0; q < 4; q++) {
            acc += e[q].y * __uint_as_float(((unsigned)u[q * 2]) << 16);
            acc += e[q].w * __uint_as_float(((unsigned)u[q * 2 + 1]) << 16);
        }
    }
    for (; k + 2 <= cnt; k += 2) {
        float4 e = *(const float4*)&s_list[k];
        unsigned short u0 = *(const unsigned short*)(hb + __float_as_int(e.x) + coff);
        unsigned short u1 = *(const unsigned short*)(hb + __float_as_int(e.z) + coff);
        acc += e.y * __uint_as_float(((unsigned)u0) << 16);
        acc += e.w * __uint_as_float(((unsigned)u1) << 16);
    }
    if (k < cnt) {
        float2 e = s_list[k];
        unsigned short u = *(const unsigned short*)(hb + __float_as_int(e.x) + coff);
        acc += e.y * __uint_as_float(((unsigned)u) << 16);
    }

    out[row * 256 + tid] = acc * inv;     // coalesced; cnt==0 -> 0
}

// ---------------------------------------------------------------------------
extern "C" void kernel_launch(void* const* d_in, const int* in_sizes, int n_in,
                              void* d_out, int out_size, void* d_ws, size_t ws_size,
                              hipStream_t stream) {
    const float* x    = (const float*)d_in[0];
    const float* adj  = (const float*)d_in[1];
    const float* mask = (const float*)d_in[2];
    const float* W    = (const float*)d_in[3];
    const float* bias = (const float*)d_in[4];
    const float* a1   = (const float*)d_in[5];
    const float* a2   = (const float*)d_in[6];
    const float* attb = (const float*)d_in[7];
    float* out = (float*)d_out;

    // workspace: h bf16 [16384*256] (8 MB) | s1b fp32 [16384] | t2 fp32 [16384]
    __hip_bfloat16* h = (__hip_bfloat16*)d_ws;
    float* s1b = (float*)((char*)d_ws + (size_t)MM * DD * 2);
    float* t2  = s1b + MM;

    gemm_h<<<dim3(MM / 64, DD / 64), 256, 0, stream>>>(x, W, bias, h);
    s_kernel<<<MM / 4, 256, 0, stream>>>(h, a1, a2, mask, attb, s1b, t2);
    attn_agg<<<MM, 256, 0, stream>>>(adj, mask, h, s1b, t2, out);
}

// Round 8
// 239.806 us; speedup vs baseline: 1.0875x; 1.0711x over previous
//
#include <hip/hip_runtime.h>
#include <hip/hip_bf16.h>

// Problem dims (fixed by reference)
#define BB 8
#define NN 2048
#define DD 256
#define MM (BB * NN)   // 16384 rows

typedef __attribute__((ext_vector_type(8))) short bf16x8_t;  // 8 bf16 = 4 VGPRs
typedef __attribute__((ext_vector_type(4))) float f32x4_t;

// ---------------------------------------------------------------------------
// Kernel A: h = x @ W^T + b. fp32 inputs, converted to bf16 at LDS staging,
// bf16 MFMA w/ fp32 accumulate, h written as bf16 (workspace).
// grid (M/64, 256/64), block 256 (4 waves).
// ---------------------------------------------------------------------------
__global__ __launch_bounds__(256) void gemm_h(
    const float* __restrict__ x,     // [M,256] fp32
    const float* __restrict__ Wt,    // [256,256] fp32 row-major [out,in] (B^T form)
    const float* __restrict__ bias,  // [256] fp32
    __hip_bfloat16* __restrict__ h)  // [M,256] bf16
{
    __shared__ __hip_bfloat16 As[64][72];
    __shared__ __hip_bfloat16 Bs[64][72];

    const int tid  = threadIdx.x;
    const int r    = tid >> 2;          // 0..63 staging row
    const int cs   = (tid & 3) * 16;    // k-segment 0/16/32/48
    const int w    = tid >> 6;          // wave 0..3
    const int lane = tid & 63;
    const int m16  = lane & 15;
    const int quad = lane >> 4;
    const long rowBase = (long)blockIdx.x * 64;
    const int  colBase = blockIdx.y * 64;

    f32x4_t acc[4];
#pragma unroll
    for (int c = 0; c < 4; c++) acc[c] = (f32x4_t){0.f, 0.f, 0.f, 0.f};

    for (int k0 = 0; k0 < 256; k0 += 64) {
        const float4* ag = (const float4*)(x  + (rowBase + r) * 256 + k0 + cs);
        const float4* bg = (const float4*)(Wt + (long)(colBase + r) * 256 + k0 + cs);
        float4 av[4], bv[4];
#pragma unroll
        for (int q = 0; q < 4; q++) { av[q] = ag[q]; bv[q] = bg[q]; }

        __align__(16) __hip_bfloat16 ta[16], tb[16];
#pragma unroll
        for (int q = 0; q < 4; q++) {
            ta[q * 4 + 0] = __float2bfloat16(av[q].x);
            ta[q * 4 + 1] = __float2bfloat16(av[q].y);
            ta[q * 4 + 2] = __float2bfloat16(av[q].z);
            ta[q * 4 + 3] = __float2bfloat16(av[q].w);
            tb[q * 4 + 0] = __float2bfloat16(bv[q].x);
            tb[q * 4 + 1] = __float2bfloat16(bv[q].y);
            tb[q * 4 + 2] = __float2bfloat16(bv[q].z);
            tb[q * 4 + 3] = __float2bfloat16(bv[q].w);
        }

        __syncthreads();
        *(uint4*)&As[r][cs]     = *(uint4*)&ta[0];
        *(uint4*)&As[r][cs + 8] = *(uint4*)&ta[8];
        *(uint4*)&Bs[r][cs]     = *(uint4*)&tb[0];
        *(uint4*)&Bs[r][cs + 8] = *(uint4*)&tb[8];
        __syncthreads();

#pragma unroll
        for (int kk = 0; kk < 64; kk += 32) {
            bf16x8_t af = *(const bf16x8_t*)&As[w * 16 + m16][kk + quad * 8];
#pragma unroll
            for (int c = 0; c < 4; c++) {
                bf16x8_t bf = *(const bf16x8_t*)&Bs[c * 16 + m16][kk + quad * 8];
                acc[c] = __builtin_amdgcn_mfma_f32_16x16x32_bf16(af, bf, acc[c], 0, 0, 0);
            }
        }
    }

    // Epilogue: C/D layout col = lane&15 (N side), row = quad*4 + reg (M side)
#pragma unroll
    for (int c = 0; c < 4; c++) {
        const int col = colBase + c * 16 + m16;
        const float bv = bias[col];
#pragma unroll
        for (int reg = 0; reg < 4; reg++) {
            const long row = rowBase + w * 16 + quad * 4 + reg;
            h[row * 256 + col] = __float2bfloat16(acc[c][reg] + bv);
        }
    }
}

// ---------------------------------------------------------------------------
// Kernel B: per row: s1b = h@a1 + att_b ; t2 = mask ? h@a2 : -1e30.
// One wave per row. t2 folds the j-side mask so attn_agg's scan is branchless:
// sigmoid(si + (-1e30)) == rcp(+inf) == 0 exactly -> masked edges drop out.
// ---------------------------------------------------------------------------
struct __attribute__((aligned(8))) bf4 { __hip_bfloat16 v[4]; };

__global__ __launch_bounds__(256) void s_kernel(
    const __hip_bfloat16* __restrict__ h,
    const float* __restrict__ a1,
    const float* __restrict__ a2,
    const float* __restrict__ mask,
    const float* __restrict__ attb_p,
    float* __restrict__ s1b, float* __restrict__ t2)
{
    const int w = threadIdx.x >> 6;
    const int lane = threadIdx.x & 63;
    const long row = (long)blockIdx.x * 4 + w;

    bf4 hv = *(const bf4*)(h + row * 256 + lane * 4);
    float4 A1 = *(const float4*)(a1 + lane * 4);
    float4 A2 = *(const float4*)(a2 + lane * 4);
    const float h0 = __bfloat162float(hv.v[0]), h1 = __bfloat162float(hv.v[1]);
    const float h2 = __bfloat162float(hv.v[2]), h3 = __bfloat162float(hv.v[3]);
    float p1 = h0 * A1.x + h1 * A1.y + h2 * A1.z + h3 * A1.w;
    float p2 = h0 * A2.x + h1 * A2.y + h2 * A2.z + h3 * A2.w;
#pragma unroll
    for (int off = 32; off; off >>= 1) {
        p1 += __shfl_down(p1, off);
        p2 += __shfl_down(p2, off);
    }
    if (lane == 0) {
        s1b[row] = p1 + attb_p[0];
        t2[row]  = (mask[row] != 0.f) ? p2 : -1e30f;
    }
}

// ---------------------------------------------------------------------------
// Kernel C: sparse attention aggregate (v8). One block per (b,i) row, 256 thr.
//  - scan (R5-proven): coalesced float4 adj+t2, branchless sigmoid, exec-
//    masked append to shared list (ushort j + float w, cap 2048 == row length
//    -> overflow structurally impossible).
//  - gather: MINIMUM wave-inst count — each neighbor is ONE wave-inst: lane
//    loads uint2 (4 channels, 64 lanes x 8B = the full 512B h row). The 4
//    waves split the list 4 ways (quarters rounded to x4 for aligned
//    ushort4/float4 uniform LDS reads). Evidence: attn_agg time tracks gather
//    wave-inst count (R2:148->79us, R5:74->61us, v7:148->80us); this is 37.
//  - cross-wave channel combine via 4KB LDS partials + 1 barrier (R5-proven
//    cheap). 3 barriers total.
// b = blockIdx & 7 keeps each batch's 1 MB h slice hot in one XCD's L2.
// ---------------------------------------------------------------------------
__global__ __launch_bounds__(256, 8) void attn_agg(
    const float* __restrict__ adj,
    const float* __restrict__ mask,
    const __hip_bfloat16* __restrict__ h,
    const float* __restrict__ s1b,
    const float* __restrict__ t2,
    float* __restrict__ out)
{
    __shared__ unsigned short s_j[2048];   // neighbor index j
    __shared__ float          s_w[2048];   // edge weight
    __shared__ float          s_part[4][DD];  // per-wave channel partials
    __shared__ int            s_cnt;
    __shared__ float          s_sum[4];

    const int tid  = threadIdx.x;
    const int wv   = tid >> 6;
    const int lane = tid & 63;
    const int b    = blockIdx.x & 7;
    const int i    = blockIdx.x >> 3;
    const long row   = (long)b * NN + i;
    const long mbase = (long)b * NN;

    const float mask_i = mask[row];
    if (mask_i == 0.f) {                  // block-uniform early exit
        out[row * 256 + tid] = 0.f;
        return;
    }
    if (tid == 0) s_cnt = 0;
    __syncthreads();

    const float si = s1b[row];
    const float4* arow = (const float4*)(adj + row * NN);
    const float4* trow = (const float4*)(t2 + mbase);

    float4 A0 = arow[tid], A1 = arow[256 + tid];   // coalesced; j = tid*4.. / 1024+tid*4..
    float4 T0 = trow[tid], T1 = trow[256 + tid];   // 64 KB array, L1/L2-hot

    float lsum = 0.f;
#pragma unroll
    for (int g = 0; g < 2; g++) {
        const int jb = g * 1024 + tid * 4;
        const float av[4] = {g ? A1.x : A0.x, g ? A1.y : A0.y, g ? A1.z : A0.z, g ? A1.w : A0.w};
        const float tv[4] = {g ? T1.x : T0.x, g ? T1.y : T0.y, g ? T1.z : T0.z, g ? T1.w : T0.w};
#pragma unroll
        for (int e = 0; e < 4; e++) {
            const float z   = si + tv[e];
            const float sig = __builtin_amdgcn_rcpf(1.f + __expf(-z));  // rcp(inf)=0 masks j
            const float wgt = av[e] * sig;
            lsum += wgt;
            if (wgt != 0.f) {             // exec-masked append, ~4.6 active lanes/block-iter
                const int pos = atomicAdd(&s_cnt, 1);
                s_j[pos] = (unsigned short)(jb + e);
                s_w[pos] = wgt;
            }
        }
    }

    // per-wave partial denominator -> LDS; barrier publishes list + sums
#pragma unroll
    for (int off = 32; off; off >>= 1) lsum += __shfl_down(lsum, off);
    if (lane == 0) s_sum[wv] = lsum;
    __syncthreads();

    const float inv = 1.f / (s_sum[0] + s_sum[1] + s_sum[2] + s_sum[3] + 1e-8f);
    const int   cnt = s_cnt;              // <= 2048 structurally

    // ---- gather: wave wv takes list quarter [ks,ke), lane owns channels
    //      [4*lane, 4*lane+4) via one uint2 load per neighbor ----
    const int qs = ((cnt + 15) >> 4) << 2;          // quarter size, multiple of 4
    const int ks = min(wv * qs, cnt);
    const int ke = min(ks + qs, cnt);
    const char* hb   = (const char*)(h + mbase * 256);  // block-uniform -> SGPR base
    const int   loff = lane * 8;

    float c0 = 0.f, c1 = 0.f, c2 = 0.f, c3 = 0.f;
    int k = ks;
    for (; k + 8 <= ke; k += 8) {
        ushort4 ja = *(const ushort4*)&s_j[k];          // aligned: ks,k multiples of 4
        ushort4 jb2 = *(const ushort4*)&s_j[k + 4];
        float4  wa = *(const float4*)&s_w[k];
        float4  wb = *(const float4*)&s_w[k + 4];
        uint2 u[8];
        u[0] = *(const uint2*)(hb + ((int)ja.x  << 9) + loff);
        u[1] = *(const uint2*)(hb + ((int)ja.y  << 9) + loff);
        u[2] = *(const uint2*)(hb + ((int)ja.z  << 9) + loff);
        u[3] = *(const uint2*)(hb + ((int)ja.w  << 9) + loff);
        u[4] = *(const uint2*)(hb + ((int)jb2.x << 9) + loff);
        u[5] = *(const uint2*)(hb + ((int)jb2.y << 9) + loff);
        u[6] = *(const uint2*)(hb + ((int)jb2.z << 9) + loff);
        u[7] = *(const uint2*)(hb + ((int)jb2.w << 9) + loff);
        const float ww[8] = {wa.x, wa.y, wa.z, wa.w, wb.x, wb.y, wb.z, wb.w};
#pragma unroll
        for (int q = 0; q < 8; q++) {
            c0 += ww[q] * __uint_as_float(u[q].x << 16);
            c1 += ww[q] * __uint_as_float(u[q].x & 0xffff0000u);
            c2 += ww[q] * __uint_as_float(u[q].y << 16);
            c3 += ww[q] * __uint_as_float(u[q].y & 0xffff0000u);
        }
    }
    for (; k + 4 <= ke; k += 4) {
        ushort4 ja = *(const ushort4*)&s_j[k];
        float4  wa = *(const float4*)&s_w[k];
        uint2 u[4];
        u[0] = *(const uint2*)(hb + ((int)ja.x << 9) + loff);
        u[1] = *(const uint2*)(hb + ((int)ja.y << 9) + loff);
        u[2] = *(const uint2*)(hb + ((int)ja.z << 9) + loff);
        u[3] = *(const uint2*)(hb + ((int)ja.w << 9) + loff);
        const float ww[4] = {wa.x, wa.y, wa.z, wa.w};
#pragma unroll
        for (int q = 0; q < 4; q++) {
            c0 += ww[q] * __uint_as_float(u[q].x << 16);
            c1 += ww[q] * __uint_as_float(u[q].x & 0xffff0000u);
            c2 += ww[q] * __uint_as_float(u[q].y << 16);
            c3 += ww[q] * __uint_as_float(u[q].y & 0xffff0000u);
        }
    }
    for (; k < ke; k++) {
        const int jj = s_j[k];
        const float wk = s_w[k];
        uint2 u = *(const uint2*)(hb + (jj << 9) + loff);
        c0 += wk * __uint_as_float(u.x << 16);
        c1 += wk * __uint_as_float(u.x & 0xffff0000u);
        c2 += wk * __uint_as_float(u.y << 16);
        c3 += wk * __uint_as_float(u.y & 0xffff0000u);
    }

    // cross-wave channel combine: 4 KB partials, one barrier
    *(float4*)&s_part[wv][lane * 4] = make_float4(c0, c1, c2, c3);
    __syncthreads();

    const float total = s_part[0][tid] + s_part[1][tid] + s_part[2][tid] + s_part[3][tid];
    out[row * 256 + tid] = total * inv;   // coalesced; cnt==0 -> 0
}

// ---------------------------------------------------------------------------
extern "C" void kernel_launch(void* const* d_in, const int* in_sizes, int n_in,
                              void* d_out, int out_size, void* d_ws, size_t ws_size,
                              hipStream_t stream) {
    const float* x    = (const float*)d_in[0];
    const float* adj  = (const float*)d_in[1];
    const float* mask = (const float*)d_in[2];
    const float* W    = (const float*)d_in[3];
    const float* bias = (const float*)d_in[4];
    const float* a1   = (const float*)d_in[5];
    const float* a2   = (const float*)d_in[6];
    const float* attb = (const float*)d_in[7];
    float* out = (float*)d_out;

    // workspace: h bf16 [16384*256] (8 MB) | s1b fp32 [16384] | t2 fp32 [16384]
    __hip_bfloat16* h = (__hip_bfloat16*)d_ws;
    float* s1b = (float*)((char*)d_ws + (size_t)MM * DD * 2);
    float* t2  = s1b + MM;

    gemm_h<<<dim3(MM / 64, DD / 64), 256, 0, stream>>>(x, W, bias, h);
    s_kernel<<<MM / 4, 256, 0, stream>>>(h, a1, a2, mask, attb, s1b, t2);
    attn_agg<<<MM, 256, 0, stream>>>(adj, mask, h, s1b, t2, out);
}